// Round 3
// baseline (153.105 us; speedup 1.0000x reference)
//
#include <hip/hip_runtime.h>

#define SEQ 1024
#define HEADS 16
#define HD 64
#define EMB 1024

typedef short bf16x8 __attribute__((ext_vector_type(8)));
typedef float f32x4 __attribute__((ext_vector_type(4)));

// float -> bf16 bits, round-to-nearest-even
static __device__ __forceinline__ unsigned short f2bf(float f) {
  unsigned u = __builtin_bit_cast(unsigned, f);
  u += 0x7FFFu + ((u >> 16) & 1u);
  return (unsigned short)(u >> 16);
}

static __device__ __forceinline__ void gload_lds16(const void* g, void* l) {
  __builtin_amdgcn_global_load_lds((const __attribute__((address_space(1))) unsigned int*)g,
                                   (__attribute__((address_space(3))) unsigned int*)l,
                                   16, 0, 0);
}

// ---------------- mask bitpack: [N,1,S,S] int32 -> mb[n][ktile][qrow] u64 ----------------
__global__ __launch_bounds__(256) void k_maskpack(const int* __restrict__ mask,
                                                  unsigned long long* __restrict__ mb) {
  const unsigned gw = (blockIdx.x * 256u + threadIdx.x) >> 6;  // n*16384 + qrow*16 + ktile
  const unsigned lane = threadIdx.x & 63u;
  const int v = mask[(size_t)gw * 64u + lane];
  const unsigned long long bits = __ballot(v != 0);
  if (lane == 0) {
    const unsigned n = gw >> 14, qrow = (gw >> 4) & 1023u, ktile = gw & 15u;
    mb[((size_t)n * 16 + ktile) * 1024 + qrow] = bits;
  }
}

// ---------------- Wo f32 -> bf16, k-dim permuted: wob[e][blk*64+4c+sub] = Wo[e][blk*64+sub*16+c] ----
__global__ __launch_bounds__(256) void k_cvtwo(const float* __restrict__ Wo,
                                               unsigned short* __restrict__ wob) {
  const unsigned gid = blockIdx.x * 256u + threadIdx.x;
  const unsigned e = gid >> 8, rem = gid & 255u;
  const unsigned blk = rem >> 4, cc = rem & 15u;
  const float* src = Wo + (size_t)e * 1024 + blk * 64 + cc;
  ushort4 o;
  o.x = f2bf(src[0]);
  o.y = f2bf(src[16]);
  o.z = f2bf(src[32]);
  o.w = f2bf(src[48]);
  ((ushort4*)wob)[gid] = o;
}

// ---------------- projections ----------------
// Q/K -> [N][H][S][Dpi] bf16 (dpos = 4*(e&15)+(e>>4));
// V  -> per-64-key-tile PV-fragment layout: addr = tile*4096 + ((e*2+ks)*4+g2)*8 + j
//       where key&63 = ks*32 + g2*8 + j (natural key order).
__global__ __launch_bounds__(256) void k_proj(const float* __restrict__ values,
                                              const float* __restrict__ query,
                                              const float* __restrict__ key,
                                              const float* __restrict__ Wv,
                                              const float* __restrict__ Wq,
                                              const float* __restrict__ Wk,
                                              unsigned short* __restrict__ vb,
                                              unsigned short* __restrict__ qb,
                                              unsigned short* __restrict__ kb) {
  const int lane = threadIdx.x & 63;
  const int c = lane & 15, g = lane >> 4;
  const int wid = blockIdx.x * 4 + (threadIdx.x >> 6);
  const int t = wid >> 12;          // 0..2
  const int rem = wid & 4095;
  const int n = rem >> 10;
  const int h = (rem >> 6) & 15;
  const int lb = rem & 63;          // 16-row block index

  const float* x; const float* W; unsigned short* out; float wscale;
  if (t == 0)      { x = values; W = Wv; out = vb; wscale = 1.0f; }
  else if (t == 1) { x = query;  W = Wq; out = qb; wscale = 0.03125f; }
  else             { x = key;    W = Wk; out = kb; wscale = 1.0f; }

  bf16x8 a[2];
  const float* xr = x + ((size_t)n * SEQ + lb * 16 + c) * EMB + h * HD;
  #pragma unroll
  for (int ks = 0; ks < 2; ++ks) {
    const float4 f0 = *(const float4*)(xr + ks * 32 + g * 8);
    const float4 f1 = *(const float4*)(xr + ks * 32 + g * 8 + 4);
    bf16x8 v;
    v[0] = (short)f2bf(f0.x); v[1] = (short)f2bf(f0.y);
    v[2] = (short)f2bf(f0.z); v[3] = (short)f2bf(f0.w);
    v[4] = (short)f2bf(f1.x); v[5] = (short)f2bf(f1.y);
    v[6] = (short)f2bf(f1.z); v[7] = (short)f2bf(f1.w);
    a[ks] = v;
  }

  f32x4 acc[4] = {};
  #pragma unroll
  for (int cb = 0; cb < 4; ++cb) {
    #pragma unroll
    for (int ks = 0; ks < 2; ++ks) {
      const float* wp = W + (cb * 16 + c) * HD + ks * 32 + g * 8;
      const float4 f0 = *(const float4*)wp;
      const float4 f1 = *(const float4*)(wp + 4);
      bf16x8 b;
      b[0] = (short)f2bf(f0.x * wscale); b[1] = (short)f2bf(f0.y * wscale);
      b[2] = (short)f2bf(f0.z * wscale); b[3] = (short)f2bf(f0.w * wscale);
      b[4] = (short)f2bf(f1.x * wscale); b[5] = (short)f2bf(f1.y * wscale);
      b[6] = (short)f2bf(f1.z * wscale); b[7] = (short)f2bf(f1.w * wscale);
      acc[cb] = __builtin_amdgcn_mfma_f32_16x16x32_bf16(a[ks], b, acc[cb], 0, 0, 0);
    }
  }

  // acc[cb][r] = out[row = lb*16+4g+r][e = cb*16+c]
  if (t == 0) {
    // V: PV-fragment layout (natural key)
    const int row0 = lb * 16 + 4 * g;
    const int tile = row0 >> 6;
    const int kk = row0 & 63;            // = 16*(lb&3) + 4*g
    const int ks = kk >> 5, g2 = (kk >> 3) & 3, j0 = kk & 7;   // j0 in {0,4}; r adds j
    unsigned short* vt = out + ((size_t)(n * HEADS + h) * SEQ + tile * 64) * HD;
    #pragma unroll
    for (int cb = 0; cb < 4; ++cb) {
      ushort4 pk;
      pk.x = f2bf(acc[cb][0]); pk.y = f2bf(acc[cb][1]);
      pk.z = f2bf(acc[cb][2]); pk.w = f2bf(acc[cb][3]);
      *(ushort4*)(vt + ((cb * 16 + c) * 2 + ks) * 32 + g2 * 8 + j0) = pk;
    }
  } else {
    unsigned short* op = out + ((size_t)(n * HEADS + h) * SEQ + lb * 16) * HD;
    #pragma unroll
    for (int r = 0; r < 4; ++r) {
      ushort4 pk;
      pk.x = f2bf(acc[0][r]); pk.y = f2bf(acc[1][r]);
      pk.z = f2bf(acc[2][r]); pk.w = f2bf(acc[3][r]);
      *(ushort4*)(op + (4 * g + r) * HD + 4 * c) = pk;
    }
  }
}

// ---------------- flash attention: no K/V staging, no barriers ----------------
// block = (n, h, 128 q-rows); 4 independent waves x 32 q-rows (2 groups of 16).
// K fragments direct from global ([S][Dpi], subtile sub / lane c <-> key 4c+sub).
// V fragments direct from global (PV-fragment layout, natural key).
// P round-trips through per-wave swizzled LDS (natural key order).
__global__ __launch_bounds__(256, 3) void k_attn(const unsigned short* __restrict__ qb,
                                                 const unsigned short* __restrict__ kb,
                                                 const unsigned short* __restrict__ vb,
                                                 const unsigned long long* __restrict__ mb,
                                                 unsigned short* __restrict__ ob) {
  const int tid = threadIdx.x;
  const int w = tid >> 6, lane = tid & 63;
  const int c = lane & 15, g = lane >> 4;
  const int bid = blockIdx.x;
  const int q128 = bid & 7, h = (bid >> 3) & 15, n = bid >> 7;
  const int qlo = q128 * 128 + w * 32;

  __shared__ unsigned short Pl[4][32][64];
  char* const Pc = (char*)&Pl[w][0][0];

  const size_t nhb = (size_t)(n * HEADS + h) * (SEQ * HD);
  const unsigned short* qp = qb + nhb;
  const unsigned short* kp = kb + nhb;
  const unsigned short* vp = vb + nhb;
  const unsigned long long* mrow = mb + ((size_t)n * 16) * SEQ + qlo;

  bf16x8 qa[2][2];
  #pragma unroll
  for (int grp = 0; grp < 2; ++grp)
    #pragma unroll
    for (int ks = 0; ks < 2; ++ks)
      qa[grp][ks] = *(const bf16x8*)(qp + (size_t)(qlo + grp * 16 + c) * HD + ks * 32 + g * 8);

  f32x4 o[2][4] = {};
  float ls[2][4] = {{0.f,0.f,0.f,0.f},{0.f,0.f,0.f,0.f}};

  for (int kt = 0; kt < 16; ++kt) {
    const unsigned short* ktp = kp + kt * 4096;
    const unsigned short* vtp = vp + kt * 4096;

    // K fragments: kf[sub][ks] lane(c,g) = K[key=4c+sub][dpos=ks*32+g*8+j]
    bf16x8 kf[4][2];
    #pragma unroll
    for (int sub = 0; sub < 4; ++sub)
      #pragma unroll
      for (int ks = 0; ks < 2; ++ks)
        kf[sub][ks] = *(const bf16x8*)(ktp + (4 * c + sub) * HD + ks * 32 + g * 8);

    // V fragments: vf[db][ks] lane(c,g) = V[key=ks*32+g*8+j][e=db*16+c]
    bf16x8 vf[4][2];
    #pragma unroll
    for (int db = 0; db < 4; ++db)
      #pragma unroll
      for (int ks = 0; ks < 2; ++ks)
        vf[db][ks] = *(const bf16x8*)(vtp + ((db * 16 + c) * 2 + ks) * 32 + g * 8);

    const unsigned long long* mk = mrow + kt * SEQ;

    #pragma unroll
    for (int grp = 0; grp < 2; ++grp) {
      f32x4 s[4];
      #pragma unroll
      for (int sub = 0; sub < 4; ++sub) {
        f32x4 acc = {};
        acc = __builtin_amdgcn_mfma_f32_16x16x32_bf16(qa[grp][0], kf[sub][0], acc, 0, 0, 0);
        acc = __builtin_amdgcn_mfma_f32_16x16x32_bf16(qa[grp][1], kf[sub][1], acc, 0, 0, 0);
        s[sub] = acc;   // col c of subtile sub = key 4c+sub
      }
      const ulonglong2 m01 = *(const ulonglong2*)(mk + grp * 16 + 4 * g);
      const ulonglong2 m23 = *(const ulonglong2*)(mk + grp * 16 + 4 * g + 2);
      const unsigned long long bitsArr[4] = {m01.x, m01.y, m23.x, m23.y};
      #pragma unroll
      for (int r = 0; r < 4; ++r) {
        const unsigned long long sh = bitsArr[r] >> (4 * c);
        const float p0 = (sh & 1ull)        ? __expf(s[0][r]) : 0.f;
        const float p1 = ((sh >> 1) & 1ull) ? __expf(s[1][r]) : 0.f;
        const float p2 = ((sh >> 2) & 1ull) ? __expf(s[2][r]) : 0.f;
        const float p3 = ((sh >> 3) & 1ull) ? __expf(s[3][r]) : 0.f;
        ls[grp][r] += (p0 + p1) + (p2 + p3);
        ushort4 pk;
        pk.x = f2bf(p0); pk.y = f2bf(p1); pk.z = f2bf(p2); pk.w = f2bf(p3);
        const int prow = grp * 16 + 4 * g + r;
        // natural key order: shorts 4c..4c+3 = keys 4c..4c+3
        *(ushort4*)(Pc + prow * 128 + ((8 * c) ^ ((prow & 7) << 4))) = pk;
      }
    }

    // O += P V
    #pragma unroll
    for (int grp = 0; grp < 2; ++grp)
      #pragma unroll
      for (int ks = 0; ks < 2; ++ks) {
        const bf16x8 pa = *(const bf16x8*)(Pc + (grp * 16 + c) * 128 +
                                           ((ks * 64 + g * 16) ^ ((c & 7) << 4)));
        #pragma unroll
        for (int db = 0; db < 4; ++db)
          o[grp][db] = __builtin_amdgcn_mfma_f32_16x16x32_bf16(pa, vf[db][ks], o[grp][db], 0, 0, 0);
      }
  }

  // epilogue: row-sum reduce (16-lane groups), normalize, packed store (Epi layout)
  #pragma unroll
  for (int grp = 0; grp < 2; ++grp)
    #pragma unroll
    for (int r = 0; r < 4; ++r) {
      float l = ls[grp][r];
      l += __shfl_xor(l, 1); l += __shfl_xor(l, 2);
      l += __shfl_xor(l, 4); l += __shfl_xor(l, 8);
      const float inv = 1.0f / l;
      ushort4 pk;
      pk.x = f2bf(o[grp][0][r] * inv);
      pk.y = f2bf(o[grp][1][r] * inv);
      pk.z = f2bf(o[grp][2][r] * inv);
      pk.w = f2bf(o[grp][3][r] * inv);
      *(ushort4*)(ob + ((size_t)n * SEQ + qlo + grp * 16 + 4 * g + r) * EMB + h * 64 + 4 * c) = pk;
    }
}

// ---------------- out-proj GEMM: C[4096,1024] = A[4096,1024pi] * B[1024,1024pi]^T + bo ----------------
// 64x128 tile, BK=64, 512 blocks (2/CU), double-buffered LDS, prefetch-before-compute.
__global__ __launch_bounds__(256) void k_gemm(const unsigned short* __restrict__ A,
                                              const unsigned short* __restrict__ B,
                                              const float* __restrict__ bo,
                                              float* __restrict__ C) {
  const int tid = threadIdx.x;
  const int w = tid >> 6, lane = tid & 63;
  const int c = lane & 15, g = lane >> 4;
  const int bm = blockIdx.x & 63, bn = blockIdx.x >> 6;
  const int m0 = bm * 64, n0 = bn * 128;

  __shared__ unsigned short As[2][64][64];
  __shared__ unsigned short Bs[2][128][64];

  f32x4 acc[4][2] = {};

#define STAGE(buf, kt_) do {                                                        \
    _Pragma("unroll")                                                               \
    for (int i = 0; i < 2; ++i) {                                                   \
      const int off = i * 4096 + tid * 16;                                          \
      const int row = off >> 7, colb = off & 127;                                   \
      gload_lds16((const char*)A + ((size_t)(m0 + row) * 1024 + (kt_) * 64) * 2 + colb, \
                  (char*)&As[buf][0][0] + off);                                     \
    }                                                                               \
    _Pragma("unroll")                                                               \
    for (int i = 0; i < 4; ++i) {                                                   \
      const int off = i * 4096 + tid * 16;                                          \
      const int row = off >> 7, colb = off & 127;                                   \
      gload_lds16((const char*)B + ((size_t)(n0 + row) * 1024 + (kt_) * 64) * 2 + colb, \
                  (char*)&Bs[buf][0][0] + off);                                     \
    }                                                                               \
  } while (0)

  STAGE(0, 0);
  __syncthreads();

  for (int kt = 0; kt < 16; ++kt) {
    const int cur = kt & 1;
    if (kt < 15) STAGE(cur ^ 1, kt + 1);
    #pragma unroll
    for (int ks = 0; ks < 2; ++ks) {
      bf16x8 af[4], bf_[2];
      #pragma unroll
      for (int i = 0; i < 4; ++i)
        af[i] = *(const bf16x8*)&As[cur][i * 16 + c][ks * 32 + g * 8];
      #pragma unroll
      for (int j = 0; j < 2; ++j)
        bf_[j] = *(const bf16x8*)&Bs[cur][w * 32 + j * 16 + c][ks * 32 + g * 8];
      #pragma unroll
      for (int i = 0; i < 4; ++i)
        #pragma unroll
        for (int j = 0; j < 2; ++j)
          acc[i][j] = __builtin_amdgcn_mfma_f32_16x16x32_bf16(af[i], bf_[j], acc[i][j], 0, 0, 0);
    }
    __syncthreads();
  }
#undef STAGE

  #pragma unroll
  for (int j = 0; j < 2; ++j) {
    const int col = n0 + w * 32 + j * 16 + c;
    const float bv = bo[col];
    #pragma unroll
    for (int i = 0; i < 4; ++i) {
      const int rowb = m0 + i * 16 + 4 * g;
      #pragma unroll
      for (int r = 0; r < 4; ++r)
        C[(size_t)(rowb + r) * 1024 + col] = acc[i][j][r] + bv;
    }
  }
}

extern "C" void kernel_launch(void* const* d_in, const int* in_sizes, int n_in,
                              void* d_out, int out_size, void* d_ws, size_t ws_size,
                              hipStream_t stream) {
  const float* values = (const float*)d_in[0];
  const float* query  = (const float*)d_in[1];
  const float* key    = (const float*)d_in[2];
  const int*   mask   = (const int*)d_in[3];
  const float* Wv     = (const float*)d_in[4];
  const float* Wk     = (const float*)d_in[5];
  const float* Wq     = (const float*)d_in[6];
  const float* Wo     = (const float*)d_in[7];
  const float* bo     = (const float*)d_in[8];
  float* out = (float*)d_out;

  char* ws = (char*)d_ws;
  unsigned short* qb = (unsigned short*)(ws);                            // 8MB  [N][H][S][Dpi]
  unsigned short* kb = (unsigned short*)(ws + (size_t)8 * 1024 * 1024);  // 8MB  [N][H][S][Dpi]
  unsigned short* vb = (unsigned short*)(ws + (size_t)16 * 1024 * 1024); // 8MB  PV-fragment tiles
  unsigned short* ob = (unsigned short*)(ws + (size_t)24 * 1024 * 1024); // 8MB  [N][S][Epi]
  unsigned long long* mb = (unsigned long long*)(ws + (size_t)32 * 1024 * 1024); // 512KB [n][kt][qrow]
  unsigned short* wob = (unsigned short*)(ws + (size_t)33 * 1024 * 1024);        // 2MB

  k_maskpack<<<16384, 256, 0, stream>>>(mask, mb);
  k_cvtwo<<<1024, 256, 0, stream>>>(Wo, wob);
  k_proj<<<3072, 256, 0, stream>>>(values, query, key, Wv, Wq, Wk, vb, qb, kb);
  k_attn<<<512, 256, 0, stream>>>(qb, kb, vb, mb, ob);
  k_gemm<<<512, 256, 0, stream>>>(ob, wob, bo, out);
}

// Round 4
// 114.562 us; speedup vs baseline: 1.3364x; 1.3364x over previous
//
#include <hip/hip_runtime.h>

#define SEQ 1024
#define HEADS 16
#define HD 64
#define EMB 1024

typedef short bf16x8 __attribute__((ext_vector_type(8)));
typedef float f32x4 __attribute__((ext_vector_type(4)));

// float -> bf16 bits, round-to-nearest-even
static __device__ __forceinline__ unsigned short f2bf(float f) {
  unsigned u = __builtin_bit_cast(unsigned, f);
  u += 0x7FFFu + ((u >> 16) & 1u);
  return (unsigned short)(u >> 16);
}

// pack two f32 -> u32 of 2 bf16 (lo = a, hi = b)
static __device__ __forceinline__ unsigned cvtpk(float a, float b) {
  unsigned r;
  asm("v_cvt_pk_bf16_f32 %0, %1, %2" : "=v"(r) : "v"(a), "v"(b));
  return r;
}

static __device__ __forceinline__ void gload_lds16(const void* g, void* l) {
  __builtin_amdgcn_global_load_lds((const __attribute__((address_space(1))) unsigned int*)g,
                                   (__attribute__((address_space(3))) unsigned int*)l,
                                   16, 0, 0);
}

// ---------------- mask bitpack: [N,1,S,S] int32 -> mb[n][ktile][qrow] u64 ----------------
__global__ __launch_bounds__(256) void k_maskpack(const int* __restrict__ mask,
                                                  unsigned long long* __restrict__ mb) {
  const unsigned gw = (blockIdx.x * 256u + threadIdx.x) >> 6;  // n*16384 + qrow*16 + ktile
  const unsigned lane = threadIdx.x & 63u;
  const int v = mask[(size_t)gw * 64u + lane];
  const unsigned long long bits = __ballot(v != 0);
  if (lane == 0) {
    const unsigned n = gw >> 14, qrow = (gw >> 4) & 1023u, ktile = gw & 15u;
    mb[((size_t)n * 16 + ktile) * 1024 + qrow] = bits;
  }
}

// ---------------- Wo f32 -> bf16, k-dim permuted: wob[e][blk*64+4c+sub] = Wo[e][blk*64+sub*16+c] ----
__global__ __launch_bounds__(256) void k_cvtwo(const float* __restrict__ Wo,
                                               unsigned short* __restrict__ wob) {
  const unsigned gid = blockIdx.x * 256u + threadIdx.x;
  const unsigned e = gid >> 8, rem = gid & 255u;
  const unsigned blk = rem >> 4, cc = rem & 15u;
  const float* src = Wo + (size_t)e * 1024 + blk * 64 + cc;
  ushort4 o;
  o.x = f2bf(src[0]);
  o.y = f2bf(src[16]);
  o.z = f2bf(src[32]);
  o.w = f2bf(src[48]);
  ((ushort4*)wob)[gid] = o;
}

// ---------------- projections ----------------
// Q/K -> [N][H][S][Dpi] bf16 (dpos = 4*(e&15)+(e>>4));  Wq scaled by log2(e)/32.
// V  -> V^T layout [N][H][D][S] bf16 (natural d, key-major rows).
__global__ __launch_bounds__(256) void k_proj(const float* __restrict__ values,
                                              const float* __restrict__ query,
                                              const float* __restrict__ key,
                                              const float* __restrict__ Wv,
                                              const float* __restrict__ Wq,
                                              const float* __restrict__ Wk,
                                              unsigned short* __restrict__ vb,
                                              unsigned short* __restrict__ qb,
                                              unsigned short* __restrict__ kb) {
  const int lane = threadIdx.x & 63;
  const int c = lane & 15, g = lane >> 4;
  const int wid = blockIdx.x * 4 + (threadIdx.x >> 6);
  const int t = wid >> 12;          // 0..2
  const int rem = wid & 4095;
  const int n = rem >> 10;
  const int h = (rem >> 6) & 15;
  const int lb = rem & 63;          // 16-row block index

  const float* x; const float* W; unsigned short* out; float wscale;
  if (t == 0)      { x = values; W = Wv; out = vb; wscale = 1.0f; }
  else if (t == 1) { x = query;  W = Wq; out = qb; wscale = 0.045084220027786356f; } // log2e/32
  else             { x = key;    W = Wk; out = kb; wscale = 1.0f; }

  bf16x8 a[2];
  const float* xr = x + ((size_t)n * SEQ + lb * 16 + c) * EMB + h * HD;
  #pragma unroll
  for (int ks = 0; ks < 2; ++ks) {
    const float4 f0 = *(const float4*)(xr + ks * 32 + g * 8);
    const float4 f1 = *(const float4*)(xr + ks * 32 + g * 8 + 4);
    bf16x8 v;
    v[0] = (short)f2bf(f0.x); v[1] = (short)f2bf(f0.y);
    v[2] = (short)f2bf(f0.z); v[3] = (short)f2bf(f0.w);
    v[4] = (short)f2bf(f1.x); v[5] = (short)f2bf(f1.y);
    v[6] = (short)f2bf(f1.z); v[7] = (short)f2bf(f1.w);
    a[ks] = v;
  }

  f32x4 acc[4] = {};
  #pragma unroll
  for (int cb = 0; cb < 4; ++cb) {
    #pragma unroll
    for (int ks = 0; ks < 2; ++ks) {
      const float* wp = W + (cb * 16 + c) * HD + ks * 32 + g * 8;
      const float4 f0 = *(const float4*)wp;
      const float4 f1 = *(const float4*)(wp + 4);
      bf16x8 b;
      b[0] = (short)f2bf(f0.x * wscale); b[1] = (short)f2bf(f0.y * wscale);
      b[2] = (short)f2bf(f0.z * wscale); b[3] = (short)f2bf(f0.w * wscale);
      b[4] = (short)f2bf(f1.x * wscale); b[5] = (short)f2bf(f1.y * wscale);
      b[6] = (short)f2bf(f1.z * wscale); b[7] = (short)f2bf(f1.w * wscale);
      acc[cb] = __builtin_amdgcn_mfma_f32_16x16x32_bf16(a[ks], b, acc[cb], 0, 0, 0);
    }
  }

  // acc[cb][r] = out[row = lb*16+4g+r][e = cb*16+c]
  if (t == 0) {
    // V^T[e][key]: keys 4g+r are consecutive -> ushort4 per cb
    unsigned short* vt = out + (size_t)(n * HEADS + h) * (HD * SEQ);
    const int key0 = lb * 16 + 4 * g;
    #pragma unroll
    for (int cb = 0; cb < 4; ++cb) {
      ushort4 pk;
      pk.x = f2bf(acc[cb][0]); pk.y = f2bf(acc[cb][1]);
      pk.z = f2bf(acc[cb][2]); pk.w = f2bf(acc[cb][3]);
      *(ushort4*)(vt + (size_t)(cb * 16 + c) * SEQ + key0) = pk;
    }
  } else {
    unsigned short* op = out + ((size_t)(n * HEADS + h) * SEQ + lb * 16) * HD;
    #pragma unroll
    for (int r = 0; r < 4; ++r) {
      ushort4 pk;
      pk.x = f2bf(acc[0][r]); pk.y = f2bf(acc[1][r]);
      pk.z = f2bf(acc[2][r]); pk.w = f2bf(acc[3][r]);
      *(ushort4*)(op + (4 * g + r) * HD + 4 * c) = pk;
    }
  }
}

// ---------------- flash attention ----------------
// block = (n, h, 128 q-rows); 4 waves x 32 q-rows (2 groups of 16).
// K + V^T staged via global_load_lds with pre-swizzled source (double-buffered).
// Max-free softmax (exp2, mask via nibble table), row-sums via MFMA-ones.
__global__ __launch_bounds__(256, 3) void k_attn(const unsigned short* __restrict__ qb,
                                                 const unsigned short* __restrict__ kb,
                                                 const unsigned short* __restrict__ vb,
                                                 const unsigned long long* __restrict__ mb,
                                                 unsigned short* __restrict__ ob) {
  const int tid = threadIdx.x;
  const int w = tid >> 6, lane = tid & 63;
  const int c = lane & 15, g = lane >> 4;
  const int bid = blockIdx.x;
  const int q128 = bid & 7, h = (bid >> 3) & 15, n = bid >> 7;
  const int qlo = q128 * 128 + w * 32;

  __shared__ unsigned short Ks[2][64][64];   // [key][dpos], XOR-swizzled slots
  __shared__ unsigned short Vs[2][64][64];   // [d][keypos], XOR-swizzled slots
  __shared__ unsigned short Pl[4][32][64];   // per-wave P, XOR-swizzled
  __shared__ uint2 Mtab[16];                 // nibble -> 2x u32 bf16-pair AND masks

  if (tid < 16) {
    const unsigned lo = ((tid & 1) ? 0xFFFFu : 0u) | ((tid & 2) ? 0xFFFF0000u : 0u);
    const unsigned hi = ((tid & 4) ? 0xFFFFu : 0u) | ((tid & 8) ? 0xFFFF0000u : 0u);
    Mtab[tid] = make_uint2(lo, hi);
  }

  char* const Kb0 = (char*)&Ks[0][0][0];
  char* const Vb0 = (char*)&Vs[0][0][0];
  char* const Pc  = (char*)&Pl[w][0][0];

  const size_t nhb = (size_t)(n * HEADS + h) * (SEQ * HD);
  const unsigned short* qp = qb + nhb;
  const char* kpB = (const char*)(kb + nhb);
  const char* vpB = (const char*)(vb + nhb);   // V^T [64][1024], row pitch 2048B

  bf16x8 qa[2][2];
  #pragma unroll
  for (int grp = 0; grp < 2; ++grp)
    #pragma unroll
    for (int ks = 0; ks < 2; ++ks)
      qa[grp][ks] = *(const bf16x8*)(qp + (size_t)(qlo + grp * 16 + c) * HD + ks * 32 + g * 8);

  bf16x8 ones;
  #pragma unroll
  for (int j = 0; j < 8; ++j) ones[j] = (short)0x3F80;

  f32x4 o[2][4] = {};
  f32x4 lacc[2] = {};

#define STAGEKV(dstK, dstV, kt_) do {                                              \
    _Pragma("unroll")                                                              \
    for (int i = 0; i < 2; ++i) {                                                  \
      const int off = i * 4096 + tid * 16;                                         \
      const int row = off >> 7, jslot = (off >> 4) & 7;                            \
      const int sw = (jslot ^ (row & 7)) << 4;                                     \
      gload_lds16(kpB + (size_t)(kt_) * 8192 + row * 128 + sw, (dstK) + off);      \
      gload_lds16(vpB + (size_t)row * 2048 + (kt_) * 128 + sw, (dstV) + off);      \
    }                                                                              \
  } while (0)

  STAGEKV(Kb0, Vb0, 0);
  __syncthreads();

  for (int kt = 0; kt < 16; ++kt) {
    const int cur = kt & 1;
    char* const Kc = Kb0 + cur * 8192;
    char* const Vc = Vb0 + cur * 8192;
    if (kt < 15) STAGEKV(Kb0 + (cur ^ 1) * 8192, Vb0 + (cur ^ 1) * 8192, kt + 1);

    // K fragments: kf[sub][ks] lane(c,g) = K[key=4c+sub][dpos=ks*32+g*8+j]
    bf16x8 kf[4][2];
    #pragma unroll
    for (int sub = 0; sub < 4; ++sub) {
      const int row = 4 * c + sub;
      #pragma unroll
      for (int ks = 0; ks < 2; ++ks)
        kf[sub][ks] = *(const bf16x8*)(Kc + row * 128 + ((ks * 64 + g * 16) ^ ((row & 7) << 4)));
    }

    const unsigned long long* mk = mb + ((size_t)(n * 16 + kt)) * 1024 + qlo;

    #pragma unroll
    for (int grp = 0; grp < 2; ++grp) {
      f32x4 s[4];
      __builtin_amdgcn_s_setprio(1);
      #pragma unroll
      for (int sub = 0; sub < 4; ++sub) {
        f32x4 acc = {};
        acc = __builtin_amdgcn_mfma_f32_16x16x32_bf16(qa[grp][0], kf[sub][0], acc, 0, 0, 0);
        acc = __builtin_amdgcn_mfma_f32_16x16x32_bf16(qa[grp][1], kf[sub][1], acc, 0, 0, 0);
        s[sub] = acc;   // col c of subtile sub = key 4c+sub (log2-domain, scaled)
      }
      __builtin_amdgcn_s_setprio(0);
      const ulonglong2 m01 = *(const ulonglong2*)(mk + grp * 16 + 4 * g);
      const ulonglong2 m23 = *(const ulonglong2*)(mk + grp * 16 + 4 * g + 2);
      const unsigned long long bitsArr[4] = {m01.x, m01.y, m23.x, m23.y};
      #pragma unroll
      for (int r = 0; r < 4; ++r) {
        const unsigned sh = (unsigned)(bitsArr[r] >> (4 * c)) & 15u;
        const uint2 me = Mtab[sh];
        const float p0 = __builtin_exp2f(s[0][r]);
        const float p1 = __builtin_exp2f(s[1][r]);
        const float p2 = __builtin_exp2f(s[2][r]);
        const float p3 = __builtin_exp2f(s[3][r]);
        const unsigned w0 = cvtpk(p0, p1) & me.x;
        const unsigned w1 = cvtpk(p2, p3) & me.y;
        const int prow = grp * 16 + 4 * g + r;
        *(uint2*)(Pc + prow * 128 + ((8 * c) ^ ((prow & 7) << 4))) = make_uint2(w0, w1);
      }
    }

    // V fragments: vf[db][ks] lane(c,g) = V^T[d=db*16+c][key=ks*32+g*8+j]
    bf16x8 vf[4][2];
    #pragma unroll
    for (int db = 0; db < 4; ++db) {
      const int row = db * 16 + c;
      #pragma unroll
      for (int ks = 0; ks < 2; ++ks)
        vf[db][ks] = *(const bf16x8*)(Vc + row * 128 + ((ks * 64 + g * 16) ^ ((row & 7) << 4)));
    }

    #pragma unroll
    for (int grp = 0; grp < 2; ++grp) {
      __builtin_amdgcn_s_setprio(1);
      #pragma unroll
      for (int ks = 0; ks < 2; ++ks) {
        const bf16x8 pa = *(const bf16x8*)(Pc + (grp * 16 + c) * 128 +
                                           ((ks * 64 + g * 16) ^ ((c & 7) << 4)));
        #pragma unroll
        for (int db = 0; db < 4; ++db)
          o[grp][db] = __builtin_amdgcn_mfma_f32_16x16x32_bf16(pa, vf[db][ks], o[grp][db], 0, 0, 0);
        lacc[grp] = __builtin_amdgcn_mfma_f32_16x16x32_bf16(pa, ones, lacc[grp], 0, 0, 0);
      }
      __builtin_amdgcn_s_setprio(0);
    }

    __syncthreads();
  }
#undef STAGEKV

  // epilogue: l already per-lane via MFMA-ones; normalize, packed store (Epi layout)
  #pragma unroll
  for (int grp = 0; grp < 2; ++grp)
    #pragma unroll
    for (int r = 0; r < 4; ++r) {
      const float inv = 1.0f / lacc[grp][r];
      const unsigned w0 = cvtpk(o[grp][0][r] * inv, o[grp][1][r] * inv);
      const unsigned w1 = cvtpk(o[grp][2][r] * inv, o[grp][3][r] * inv);
      *(uint2*)(ob + ((size_t)n * SEQ + qlo + grp * 16 + 4 * g + r) * EMB + h * 64 + 4 * c) =
          make_uint2(w0, w1);
    }
}

// ---------------- out-proj GEMM: C[4096,1024] = A[4096,1024pi] * B[1024,1024pi]^T + bo ----------------
// 64x128 tile, BK=64, 512 blocks (2/CU), double-buffered LDS, prefetch-before-compute.
__global__ __launch_bounds__(256) void k_gemm(const unsigned short* __restrict__ A,
                                              const unsigned short* __restrict__ B,
                                              const float* __restrict__ bo,
                                              float* __restrict__ C) {
  const int tid = threadIdx.x;
  const int w = tid >> 6, lane = tid & 63;
  const int c = lane & 15, g = lane >> 4;
  const int bm = blockIdx.x & 63, bn = blockIdx.x >> 6;
  const int m0 = bm * 64, n0 = bn * 128;

  __shared__ unsigned short As[2][64][64];
  __shared__ unsigned short Bs[2][128][64];

  f32x4 acc[4][2] = {};

#define STAGE(buf, kt_) do {                                                        \
    _Pragma("unroll")                                                               \
    for (int i = 0; i < 2; ++i) {                                                   \
      const int off = i * 4096 + tid * 16;                                          \
      const int row = off >> 7, colb = off & 127;                                   \
      gload_lds16((const char*)A + ((size_t)(m0 + row) * 1024 + (kt_) * 64) * 2 + colb, \
                  (char*)&As[buf][0][0] + off);                                     \
    }                                                                               \
    _Pragma("unroll")                                                               \
    for (int i = 0; i < 4; ++i) {                                                   \
      const int off = i * 4096 + tid * 16;                                          \
      const int row = off >> 7, colb = off & 127;                                   \
      gload_lds16((const char*)B + ((size_t)(n0 + row) * 1024 + (kt_) * 64) * 2 + colb, \
                  (char*)&Bs[buf][0][0] + off);                                     \
    }                                                                               \
  } while (0)

  STAGE(0, 0);
  __syncthreads();

  for (int kt = 0; kt < 16; ++kt) {
    const int cur = kt & 1;
    if (kt < 15) STAGE(cur ^ 1, kt + 1);
    #pragma unroll
    for (int ks = 0; ks < 2; ++ks) {
      bf16x8 af[4], bf_[2];
      #pragma unroll
      for (int i = 0; i < 4; ++i)
        af[i] = *(const bf16x8*)&As[cur][i * 16 + c][ks * 32 + g * 8];
      #pragma unroll
      for (int j = 0; j < 2; ++j)
        bf_[j] = *(const bf16x8*)&Bs[cur][w * 32 + j * 16 + c][ks * 32 + g * 8];
      #pragma unroll
      for (int i = 0; i < 4; ++i)
        #pragma unroll
        for (int j = 0; j < 2; ++j)
          acc[i][j] = __builtin_amdgcn_mfma_f32_16x16x32_bf16(af[i], bf_[j], acc[i][j], 0, 0, 0);
    }
    __syncthreads();
  }
#undef STAGE

  #pragma unroll
  for (int j = 0; j < 2; ++j) {
    const int col = n0 + w * 32 + j * 16 + c;
    const float bv = bo[col];
    #pragma unroll
    for (int i = 0; i < 4; ++i) {
      const int rowb = m0 + i * 16 + 4 * g;
      #pragma unroll
      for (int r = 0; r < 4; ++r)
        C[(size_t)(rowb + r) * 1024 + col] = acc[i][j][r] + bv;
    }
  }
}

extern "C" void kernel_launch(void* const* d_in, const int* in_sizes, int n_in,
                              void* d_out, int out_size, void* d_ws, size_t ws_size,
                              hipStream_t stream) {
  const float* values = (const float*)d_in[0];
  const float* query  = (const float*)d_in[1];
  const float* key    = (const float*)d_in[2];
  const int*   mask   = (const int*)d_in[3];
  const float* Wv     = (const float*)d_in[4];
  const float* Wk     = (const float*)d_in[5];
  const float* Wq     = (const float*)d_in[6];
  const float* Wo     = (const float*)d_in[7];
  const float* bo     = (const float*)d_in[8];
  float* out = (float*)d_out;

  char* ws = (char*)d_ws;
  unsigned short* qb = (unsigned short*)(ws);                            // 8MB  [N][H][S][Dpi]
  unsigned short* kb = (unsigned short*)(ws + (size_t)8 * 1024 * 1024);  // 8MB  [N][H][S][Dpi]
  unsigned short* vb = (unsigned short*)(ws + (size_t)16 * 1024 * 1024); // 8MB  V^T [N][H][D][S]
  unsigned short* ob = (unsigned short*)(ws + (size_t)24 * 1024 * 1024); // 8MB  [N][S][Epi]
  unsigned long long* mb = (unsigned long long*)(ws + (size_t)32 * 1024 * 1024); // 512KB [n][kt][qrow]
  unsigned short* wob = (unsigned short*)(ws + (size_t)33 * 1024 * 1024);        // 2MB

  k_maskpack<<<16384, 256, 0, stream>>>(mask, mb);
  k_cvtwo<<<1024, 256, 0, stream>>>(Wo, wob);
  k_proj<<<3072, 256, 0, stream>>>(values, query, key, Wv, Wq, Wk, vb, qb, kb);
  k_attn<<<512, 256, 0, stream>>>(qb, kb, vb, mb, ob);
  k_gemm<<<512, 256, 0, stream>>>(ob, wob, bo, out);
}

// Round 5
// 98.382 us; speedup vs baseline: 1.5562x; 1.1645x over previous
//
#include <hip/hip_runtime.h>

#define SEQ 1024
#define HEADS 16
#define HD 64
#define EMB 1024

typedef short bf16x8 __attribute__((ext_vector_type(8)));
typedef float f32x4 __attribute__((ext_vector_type(4)));

// float -> bf16 bits, round-to-nearest-even
static __device__ __forceinline__ unsigned short f2bf(float f) {
  unsigned u = __builtin_bit_cast(unsigned, f);
  u += 0x7FFFu + ((u >> 16) & 1u);
  return (unsigned short)(u >> 16);
}

// pack two f32 -> u32 of 2 bf16 (lo = a, hi = b)
static __device__ __forceinline__ unsigned cvtpk(float a, float b) {
  unsigned r;
  asm("v_cvt_pk_bf16_f32 %0, %1, %2" : "=v"(r) : "v"(a), "v"(b));
  return r;
}

static __device__ __forceinline__ void gload_lds16(const void* g, void* l) {
  __builtin_amdgcn_global_load_lds((const __attribute__((address_space(1))) unsigned int*)g,
                                   (__attribute__((address_space(3))) unsigned int*)l,
                                   16, 0, 0);
}

// ---------------- mask bitpack: [N,1,S,S] int32 -> mb[n][ktile][qrow] u64 ----------------
__global__ __launch_bounds__(256) void k_maskpack(const int* __restrict__ mask,
                                                  unsigned long long* __restrict__ mb) {
  const unsigned gw = (blockIdx.x * 256u + threadIdx.x) >> 6;  // n*16384 + qrow*16 + ktile
  const unsigned lane = threadIdx.x & 63u;
  const int v = mask[(size_t)gw * 64u + lane];
  const unsigned long long bits = __ballot(v != 0);
  if (lane == 0) {
    const unsigned n = gw >> 14, qrow = (gw >> 4) & 1023u, ktile = gw & 15u;
    mb[((size_t)n * 16 + ktile) * 1024 + qrow] = bits;
  }
}

// ---------------- weight prep ----------------
// blocks < 1024: Wo f32 -> bf16, k-dim permuted: wob[e][blk*64+4c+sub] = Wo[e][blk*64+sub*16+c]
// block 1024: Wv/Wq/Wk -> bf16 row-major (Wq scaled by log2(e)/32)
__global__ __launch_bounds__(256) void k_cvtwo(const float* __restrict__ Wo,
                                               const float* __restrict__ Wv,
                                               const float* __restrict__ Wq,
                                               const float* __restrict__ Wk,
                                               unsigned short* __restrict__ wob,
                                               unsigned short* __restrict__ wb) {
  const unsigned tid = threadIdx.x;
  if (blockIdx.x < 1024) {
    const unsigned gid = blockIdx.x * 256u + tid;
    const unsigned e = gid >> 8, rem = gid & 255u;
    const unsigned blk = rem >> 4, cc = rem & 15u;
    const float* src = Wo + (size_t)e * 1024 + blk * 64 + cc;
    const unsigned w0 = cvtpk(src[0], src[16]);
    const unsigned w1 = cvtpk(src[32], src[48]);
    *(uint2*)(wob + (size_t)gid * 4) = make_uint2(w0, w1);
  } else {
    #pragma unroll
    for (int t = 0; t < 3; ++t) {
      const float* src = (t == 0) ? Wv : (t == 1) ? Wq : Wk;
      const float sc = (t == 1) ? 0.045084220027786356f : 1.0f;  // log2e/32 for Wq
      const float4 f0 = *(const float4*)(src + tid * 16);
      const float4 f1 = *(const float4*)(src + tid * 16 + 4);
      const float4 f2 = *(const float4*)(src + tid * 16 + 8);
      const float4 f3 = *(const float4*)(src + tid * 16 + 12);
      uint4 u0, u1;
      u0.x = cvtpk(f0.x * sc, f0.y * sc); u0.y = cvtpk(f0.z * sc, f0.w * sc);
      u0.z = cvtpk(f1.x * sc, f1.y * sc); u0.w = cvtpk(f1.z * sc, f1.w * sc);
      u1.x = cvtpk(f2.x * sc, f2.y * sc); u1.y = cvtpk(f2.z * sc, f2.w * sc);
      u1.z = cvtpk(f3.x * sc, f3.y * sc); u1.w = cvtpk(f3.z * sc, f3.w * sc);
      *(uint4*)(wb + t * 4096 + tid * 16) = u0;
      *(uint4*)(wb + t * 4096 + tid * 16 + 8) = u1;
    }
  }
}

// ---------------- projections ----------------
// Q/K -> [N][H][S][Dpi] bf16 (dpos = 4*(e&15)+(e>>4));  V -> V^T [N][H][D][S] bf16.
// W read pre-converted bf16 (wb[t][e][d] row-major).
__global__ __launch_bounds__(256) void k_proj(const float* __restrict__ values,
                                              const float* __restrict__ query,
                                              const float* __restrict__ key,
                                              const unsigned short* __restrict__ wb,
                                              unsigned short* __restrict__ vb,
                                              unsigned short* __restrict__ qb,
                                              unsigned short* __restrict__ kb) {
  const int lane = threadIdx.x & 63;
  const int c = lane & 15, g = lane >> 4;
  const int wid = blockIdx.x * 4 + (threadIdx.x >> 6);
  const int t = wid >> 12;          // 0..2
  const int rem = wid & 4095;
  const int n = rem >> 10;
  const int h = (rem >> 6) & 15;
  const int lb = rem & 63;          // 16-row block index

  const float* x; unsigned short* out;
  if (t == 0)      { x = values; out = vb; }
  else if (t == 1) { x = query;  out = qb; }
  else             { x = key;    out = kb; }
  const unsigned short* W = wb + t * 4096;

  bf16x8 a[2];
  const float* xr = x + ((size_t)n * SEQ + lb * 16 + c) * EMB + h * HD;
  #pragma unroll
  for (int ks = 0; ks < 2; ++ks) {
    const float4 f0 = *(const float4*)(xr + ks * 32 + g * 8);
    const float4 f1 = *(const float4*)(xr + ks * 32 + g * 8 + 4);
    uint4 u;
    u.x = cvtpk(f0.x, f0.y); u.y = cvtpk(f0.z, f0.w);
    u.z = cvtpk(f1.x, f1.y); u.w = cvtpk(f1.z, f1.w);
    a[ks] = __builtin_bit_cast(bf16x8, u);
  }

  f32x4 acc[4] = {};
  #pragma unroll
  for (int cb = 0; cb < 4; ++cb) {
    #pragma unroll
    for (int ks = 0; ks < 2; ++ks) {
      // B[k=d][col=e]: lane(c,g) reads Wb[e=cb*16+c][d=ks*32+g*8 ..+7]
      const bf16x8 b = *(const bf16x8*)(W + (cb * 16 + c) * HD + ks * 32 + g * 8);
      acc[cb] = __builtin_amdgcn_mfma_f32_16x16x32_bf16(a[ks], b, acc[cb], 0, 0, 0);
    }
  }

  // acc[cb][r] = out[row = lb*16+4g+r][e = cb*16+c]
  if (t == 0) {
    // V^T[e][key]: keys 4g+r are consecutive -> 8B store per cb
    unsigned short* vt = out + (size_t)(n * HEADS + h) * (HD * SEQ);
    const int key0 = lb * 16 + 4 * g;
    #pragma unroll
    for (int cb = 0; cb < 4; ++cb) {
      const unsigned w0 = cvtpk(acc[cb][0], acc[cb][1]);
      const unsigned w1 = cvtpk(acc[cb][2], acc[cb][3]);
      *(uint2*)(vt + (size_t)(cb * 16 + c) * SEQ + key0) = make_uint2(w0, w1);
    }
  } else {
    unsigned short* op = out + ((size_t)(n * HEADS + h) * SEQ + lb * 16) * HD;
    #pragma unroll
    for (int r = 0; r < 4; ++r) {
      const unsigned w0 = cvtpk(acc[0][r], acc[1][r]);
      const unsigned w1 = cvtpk(acc[2][r], acc[3][r]);
      *(uint2*)(op + (4 * g + r) * HD + 4 * c) = make_uint2(w0, w1);
    }
  }
}

// ---------------- flash attention ----------------
// block = (n, h, 64 q-rows); 4 waves x 16 q-rows. Grid 1024, bid%8 = nh%8 (XCD locality).
// K + V^T staged via global_load_lds, pre-swizzled source, double-buffered.
// Max-free softmax (exp2, mask nibble table), row-sums via MFMA-ones.
__global__ __launch_bounds__(256, 3) void k_attn(const unsigned short* __restrict__ qb,
                                                 const unsigned short* __restrict__ kb,
                                                 const unsigned short* __restrict__ vb,
                                                 const unsigned long long* __restrict__ mb,
                                                 unsigned short* __restrict__ ob) {
  const int tid = threadIdx.x;
  const int w = tid >> 6, lane = tid & 63;
  const int c = lane & 15, g = lane >> 4;
  const int bid = blockIdx.x;
  const int nh = bid & 63, q64 = bid >> 6;
  const int n = nh >> 4, h = nh & 15;
  const int qlo = q64 * 64 + w * 16;

  __shared__ unsigned short Ks[2][64][64];   // [key][dpos], swz slot ^= (row>>2)&7
  __shared__ unsigned short Vs[2][64][64];   // [d][keypos], swz slot ^= row&7
  __shared__ unsigned short Pl[4][16][64];   // per-wave P, swz slot ^= row&7
  __shared__ uint2 Mtab[16];                 // nibble -> 2x u32 bf16-pair AND masks

  if (tid < 16) {
    const unsigned lo = ((tid & 1) ? 0xFFFFu : 0u) | ((tid & 2) ? 0xFFFF0000u : 0u);
    const unsigned hi = ((tid & 4) ? 0xFFFFu : 0u) | ((tid & 8) ? 0xFFFF0000u : 0u);
    Mtab[tid] = make_uint2(lo, hi);
  }

  char* const Kb0 = (char*)&Ks[0][0][0];
  char* const Vb0 = (char*)&Vs[0][0][0];
  char* const Pc  = (char*)&Pl[w][0][0];

  const size_t nhb = (size_t)(n * HEADS + h) * (SEQ * HD);
  const unsigned short* qp = qb + nhb;
  const char* kpB = (const char*)(kb + nhb);
  const char* vpB = (const char*)(vb + nhb);   // V^T [64][1024], row pitch 2048B

  bf16x8 qa[2];
  #pragma unroll
  for (int ks = 0; ks < 2; ++ks)
    qa[ks] = *(const bf16x8*)(qp + (size_t)(qlo + c) * HD + ks * 32 + g * 8);

  bf16x8 ones;
  #pragma unroll
  for (int j = 0; j < 8; ++j) ones[j] = (short)0x3F80;

  f32x4 o[4] = {};
  f32x4 lacc = {};

#define STAGEKV(dstK, dstV, kt_) do {                                                   \
    _Pragma("unroll")                                                                   \
    for (int i = 0; i < 2; ++i) {                                                       \
      const int off = i * 4096 + tid * 16;                                              \
      const int row = off >> 7, slot = (off >> 4) & 7;                                  \
      gload_lds16(kpB + (size_t)(kt_) * 8192 + row * 128 + ((slot ^ ((row >> 2) & 7)) << 4), \
                  (dstK) + off);                                                        \
      gload_lds16(vpB + (size_t)row * 2048 + (kt_) * 128 + ((slot ^ (row & 7)) << 4),   \
                  (dstV) + off);                                                        \
    }                                                                                   \
  } while (0)

  STAGEKV(Kb0, Vb0, 0);
  __syncthreads();

  for (int kt = 0; kt < 16; ++kt) {
    const int cur = kt & 1;
    char* const Kc = Kb0 + cur * 8192;
    char* const Vc = Vb0 + cur * 8192;
    if (kt < 15) STAGEKV(Kb0 + (cur ^ 1) * 8192, Vb0 + (cur ^ 1) * 8192, kt + 1);

    // K fragments: kf[sub][ks] lane(c,g) = K[key=4c+sub][dpos=ks*32+g*8+j]; row>>2 == c
    bf16x8 kf[4][2];
    #pragma unroll
    for (int sub = 0; sub < 4; ++sub) {
      const int row = 4 * c + sub;
      #pragma unroll
      for (int ks = 0; ks < 2; ++ks)
        kf[sub][ks] = *(const bf16x8*)(Kc + row * 128 + (((ks * 4 + g) ^ (c & 7)) << 4));
    }

    f32x4 s[4];
    __builtin_amdgcn_s_setprio(1);
    #pragma unroll
    for (int sub = 0; sub < 4; ++sub) {
      f32x4 acc = {};
      acc = __builtin_amdgcn_mfma_f32_16x16x32_bf16(qa[0], kf[sub][0], acc, 0, 0, 0);
      acc = __builtin_amdgcn_mfma_f32_16x16x32_bf16(qa[1], kf[sub][1], acc, 0, 0, 0);
      s[sub] = acc;   // col c of subtile sub = key 4c+sub (log2-domain, scaled)
    }
    __builtin_amdgcn_s_setprio(0);

    const unsigned long long* mk = mb + ((size_t)(n * 16 + kt)) * 1024 + qlo;
    const ulonglong2 m01 = *(const ulonglong2*)(mk + 4 * g);
    const ulonglong2 m23 = *(const ulonglong2*)(mk + 4 * g + 2);
    const unsigned long long bitsArr[4] = {m01.x, m01.y, m23.x, m23.y};
    #pragma unroll
    for (int r = 0; r < 4; ++r) {
      const unsigned sh = (unsigned)(bitsArr[r] >> (4 * c)) & 15u;
      const uint2 me = Mtab[sh];
      const float p0 = __builtin_exp2f(s[0][r]);
      const float p1 = __builtin_exp2f(s[1][r]);
      const float p2 = __builtin_exp2f(s[2][r]);
      const float p3 = __builtin_exp2f(s[3][r]);
      const unsigned w0 = cvtpk(p0, p1) & me.x;
      const unsigned w1 = cvtpk(p2, p3) & me.y;
      const int prow = 4 * g + r;
      *(uint2*)(Pc + prow * 128 + ((8 * c) ^ ((prow & 7) << 4))) = make_uint2(w0, w1);
    }

    // V fragments: vf[db][ks] lane(c,g) = V^T[d=db*16+c][key=ks*32+g*8+j]; row&7 == c&7
    bf16x8 vf[4][2];
    #pragma unroll
    for (int db = 0; db < 4; ++db) {
      const int row = db * 16 + c;
      #pragma unroll
      for (int ks = 0; ks < 2; ++ks)
        vf[db][ks] = *(const bf16x8*)(Vc + row * 128 + (((ks * 4 + g) ^ (c & 7)) << 4));
    }

    __builtin_amdgcn_s_setprio(1);
    #pragma unroll
    for (int ks = 0; ks < 2; ++ks) {
      const bf16x8 pa = *(const bf16x8*)(Pc + c * 128 + (((ks * 4 + g) ^ (c & 7)) << 4));
      #pragma unroll
      for (int db = 0; db < 4; ++db)
        o[db] = __builtin_amdgcn_mfma_f32_16x16x32_bf16(pa, vf[db][ks], o[db], 0, 0, 0);
      lacc = __builtin_amdgcn_mfma_f32_16x16x32_bf16(pa, ones, lacc, 0, 0, 0);
    }
    __builtin_amdgcn_s_setprio(0);

    __syncthreads();
  }
#undef STAGEKV

  // epilogue: l per-lane via MFMA-ones; normalize, packed store (Epi layout)
  #pragma unroll
  for (int r = 0; r < 4; ++r) {
    const float inv = 1.0f / lacc[r];
    const unsigned w0 = cvtpk(o[0][r] * inv, o[1][r] * inv);
    const unsigned w1 = cvtpk(o[2][r] * inv, o[3][r] * inv);
    *(uint2*)(ob + ((size_t)n * SEQ + qlo + 4 * g + r) * EMB + h * 64 + 4 * c) =
        make_uint2(w0, w1);
  }
}

// ---------------- out-proj GEMM: C[4096,1024] = A[4096,1024pi] * B[1024,1024pi]^T + bo ----------------
// 64x64 tile, BK=64, grid 1024 (4/CU), swizzled dbuf LDS, bid%8 = bm%8 (XCD: A-band locality).
__global__ __launch_bounds__(256, 4) void k_gemm(const unsigned short* __restrict__ A,
                                                 const unsigned short* __restrict__ B,
                                                 const float* __restrict__ bo,
                                                 float* __restrict__ C) {
  const int tid = threadIdx.x;
  const int w = tid >> 6, lane = tid & 63;
  const int c = lane & 15, g = lane >> 4;
  const int bm = blockIdx.x & 63, bn = blockIdx.x >> 6;
  const int m0 = bm * 64, n0 = bn * 64;
  const int wr = w >> 1, wc = w & 1;

  __shared__ unsigned short As[2][64][64];
  __shared__ unsigned short Bs[2][64][64];

  f32x4 acc[2][2] = {};

#define STAGE(buf, kt_) do {                                                             \
    _Pragma("unroll")                                                                    \
    for (int i = 0; i < 2; ++i) {                                                        \
      const int off = i * 4096 + tid * 16;                                               \
      const int row = off >> 7, slot = (off >> 4) & 7;                                   \
      const int sw = (slot ^ (row & 7)) << 4;                                            \
      gload_lds16((const char*)A + ((size_t)(m0 + row) * 1024 + (kt_) * 64) * 2 + sw,    \
                  (char*)&As[buf][0][0] + off);                                          \
      gload_lds16((const char*)B + ((size_t)(n0 + row) * 1024 + (kt_) * 64) * 2 + sw,    \
                  (char*)&Bs[buf][0][0] + off);                                          \
    }                                                                                    \
  } while (0)

  STAGE(0, 0);
  __syncthreads();

  for (int kt = 0; kt < 16; ++kt) {
    const int cur = kt & 1;
    if (kt < 15) STAGE(cur ^ 1, kt + 1);
    #pragma unroll
    for (int ks = 0; ks < 2; ++ks) {
      bf16x8 af[2], bf_[2];
      #pragma unroll
      for (int i = 0; i < 2; ++i) {
        const int row = wr * 32 + i * 16 + c;   // row&7 == c&7
        af[i] = *(const bf16x8*)((char*)&As[cur][0][0] + row * 128 +
                                 (((ks * 4 + g) ^ (c & 7)) << 4));
      }
      #pragma unroll
      for (int j = 0; j < 2; ++j) {
        const int row = wc * 32 + j * 16 + c;
        bf_[j] = *(const bf16x8*)((char*)&Bs[cur][0][0] + row * 128 +
                                  (((ks * 4 + g) ^ (c & 7)) << 4));
      }
      __builtin_amdgcn_s_setprio(1);
      #pragma unroll
      for (int i = 0; i < 2; ++i)
        #pragma unroll
        for (int j = 0; j < 2; ++j)
          acc[i][j] = __builtin_amdgcn_mfma_f32_16x16x32_bf16(af[i], bf_[j], acc[i][j], 0, 0, 0);
      __builtin_amdgcn_s_setprio(0);
    }
    __syncthreads();
  }
#undef STAGE

  #pragma unroll
  for (int j = 0; j < 2; ++j) {
    const int col = n0 + wc * 32 + j * 16 + c;
    const float bv = bo[col];
    #pragma unroll
    for (int i = 0; i < 2; ++i) {
      const int rowb = m0 + wr * 32 + i * 16 + 4 * g;
      #pragma unroll
      for (int r = 0; r < 4; ++r)
        C[(size_t)(rowb + r) * 1024 + col] = acc[i][j][r] + bv;
    }
  }
}

extern "C" void kernel_launch(void* const* d_in, const int* in_sizes, int n_in,
                              void* d_out, int out_size, void* d_ws, size_t ws_size,
                              hipStream_t stream) {
  const float* values = (const float*)d_in[0];
  const float* query  = (const float*)d_in[1];
  const float* key    = (const float*)d_in[2];
  const int*   mask   = (const int*)d_in[3];
  const float* Wv     = (const float*)d_in[4];
  const float* Wk     = (const float*)d_in[5];
  const float* Wq     = (const float*)d_in[6];
  const float* Wo     = (const float*)d_in[7];
  const float* bo     = (const float*)d_in[8];
  float* out = (float*)d_out;

  char* ws = (char*)d_ws;
  unsigned short* qb = (unsigned short*)(ws);                            // 8MB  [N][H][S][Dpi]
  unsigned short* kb = (unsigned short*)(ws + (size_t)8 * 1024 * 1024);  // 8MB  [N][H][S][Dpi]
  unsigned short* vb = (unsigned short*)(ws + (size_t)16 * 1024 * 1024); // 8MB  V^T [N][H][D][S]
  unsigned short* ob = (unsigned short*)(ws + (size_t)24 * 1024 * 1024); // 8MB  [N][S][Epi]
  unsigned long long* mb = (unsigned long long*)(ws + (size_t)32 * 1024 * 1024);   // 512KB
  unsigned short* wb  = (unsigned short*)(ws + (size_t)32 * 1024 * 1024 + 512 * 1024); // 24KB
  unsigned short* wob = (unsigned short*)(ws + (size_t)33 * 1024 * 1024);          // 2MB

  k_maskpack<<<16384, 256, 0, stream>>>(mask, mb);
  k_cvtwo<<<1025, 256, 0, stream>>>(Wo, Wv, Wq, Wk, wob, wb);
  k_proj<<<3072, 256, 0, stream>>>(values, query, key, wb, vb, qb, kb);
  k_attn<<<1024, 256, 0, stream>>>(qb, kb, vb, mb, ob);
  k_gemm<<<1024, 256, 0, stream>>>(ob, wob, bo, out);
}

// Round 6
// 86.314 us; speedup vs baseline: 1.7738x; 1.1398x over previous
//
#include <hip/hip_runtime.h>

#define SEQ 1024
#define HEADS 16
#define HD 64
#define EMB 1024

typedef short bf16x8 __attribute__((ext_vector_type(8)));
typedef float f32x4 __attribute__((ext_vector_type(4)));

// float -> bf16 bits, round-to-nearest-even
static __device__ __forceinline__ unsigned short f2bf(float f) {
  unsigned u = __builtin_bit_cast(unsigned, f);
  u += 0x7FFFu + ((u >> 16) & 1u);
  return (unsigned short)(u >> 16);
}

// pack two f32 -> u32 of 2 bf16 (lo = a, hi = b)
static __device__ __forceinline__ unsigned cvtpk(float a, float b) {
  unsigned r;
  asm("v_cvt_pk_bf16_f32 %0, %1, %2" : "=v"(r) : "v"(a), "v"(b));
  return r;
}

static __device__ __forceinline__ void gload_lds16(const void* g, void* l) {
  __builtin_amdgcn_global_load_lds((const __attribute__((address_space(1))) unsigned int*)g,
                                   (__attribute__((address_space(3))) unsigned int*)l,
                                   16, 0, 0);
}

// ---------------- mask bitpack: [N,1,S,S] int32 -> mb[n][ktile][qrow] u64 ----------------
__global__ __launch_bounds__(256) void k_maskpack(const int* __restrict__ mask,
                                                  unsigned long long* __restrict__ mb) {
  const unsigned gw = (blockIdx.x * 256u + threadIdx.x) >> 6;  // n*16384 + qrow*16 + ktile
  const unsigned lane = threadIdx.x & 63u;
  const int v = mask[(size_t)gw * 64u + lane];
  const unsigned long long bits = __ballot(v != 0);
  if (lane == 0) {
    const unsigned n = gw >> 14, qrow = (gw >> 4) & 1023u, ktile = gw & 15u;
    mb[((size_t)n * 16 + ktile) * 1024 + qrow] = bits;
  }
}

// ---------------- weight prep ----------------
// blocks < 1024: Wo f32 -> bf16, k-dim permuted: wob[e][blk*64+4c+sub] = Wo[e][blk*64+sub*16+c]
// block 1024: Wv/Wq/Wk -> bf16 row-major (Wq scaled by log2(e)/32)
__global__ __launch_bounds__(256) void k_cvtwo(const float* __restrict__ Wo,
                                               const float* __restrict__ Wv,
                                               const float* __restrict__ Wq,
                                               const float* __restrict__ Wk,
                                               unsigned short* __restrict__ wob,
                                               unsigned short* __restrict__ wb) {
  const unsigned tid = threadIdx.x;
  if (blockIdx.x < 1024) {
    const unsigned gid = blockIdx.x * 256u + tid;
    const unsigned e = gid >> 8, rem = gid & 255u;
    const unsigned blk = rem >> 4, cc = rem & 15u;
    const float* src = Wo + (size_t)e * 1024 + blk * 64 + cc;
    const unsigned w0 = cvtpk(src[0], src[16]);
    const unsigned w1 = cvtpk(src[32], src[48]);
    *(uint2*)(wob + (size_t)gid * 4) = make_uint2(w0, w1);
  } else {
    #pragma unroll
    for (int t = 0; t < 3; ++t) {
      const float* src = (t == 0) ? Wv : (t == 1) ? Wq : Wk;
      const float sc = (t == 1) ? 0.045084220027786356f : 1.0f;  // log2e/32 for Wq
      const float4 f0 = *(const float4*)(src + tid * 16);
      const float4 f1 = *(const float4*)(src + tid * 16 + 4);
      const float4 f2 = *(const float4*)(src + tid * 16 + 8);
      const float4 f3 = *(const float4*)(src + tid * 16 + 12);
      uint4 u0, u1;
      u0.x = cvtpk(f0.x * sc, f0.y * sc); u0.y = cvtpk(f0.z * sc, f0.w * sc);
      u0.z = cvtpk(f1.x * sc, f1.y * sc); u0.w = cvtpk(f1.z * sc, f1.w * sc);
      u1.x = cvtpk(f2.x * sc, f2.y * sc); u1.y = cvtpk(f2.z * sc, f2.w * sc);
      u1.z = cvtpk(f3.x * sc, f3.y * sc); u1.w = cvtpk(f3.z * sc, f3.w * sc);
      *(uint4*)(wb + t * 4096 + tid * 16) = u0;
      *(uint4*)(wb + t * 4096 + tid * 16 + 8) = u1;
    }
  }
}

// ---------------- projections ----------------
// Q/K -> [N][H][S][Dpi] bf16 (dpos = 4*(e&15)+(e>>4));  V -> V^T [N][H][D][S] bf16.
// W read pre-converted bf16 (wb[t][e][d] row-major).
__global__ __launch_bounds__(256) void k_proj(const float* __restrict__ values,
                                              const float* __restrict__ query,
                                              const float* __restrict__ key,
                                              const unsigned short* __restrict__ wb,
                                              unsigned short* __restrict__ vb,
                                              unsigned short* __restrict__ qb,
                                              unsigned short* __restrict__ kb) {
  const int lane = threadIdx.x & 63;
  const int c = lane & 15, g = lane >> 4;
  const int wid = blockIdx.x * 4 + (threadIdx.x >> 6);
  const int t = wid >> 12;          // 0..2
  const int rem = wid & 4095;
  const int n = rem >> 10;
  const int h = (rem >> 6) & 15;
  const int lb = rem & 63;          // 16-row block index

  const float* x; unsigned short* out;
  if (t == 0)      { x = values; out = vb; }
  else if (t == 1) { x = query;  out = qb; }
  else             { x = key;    out = kb; }
  const unsigned short* W = wb + t * 4096;

  bf16x8 a[2];
  const float* xr = x + ((size_t)n * SEQ + lb * 16 + c) * EMB + h * HD;
  #pragma unroll
  for (int ks = 0; ks < 2; ++ks) {
    const float4 f0 = *(const float4*)(xr + ks * 32 + g * 8);
    const float4 f1 = *(const float4*)(xr + ks * 32 + g * 8 + 4);
    uint4 u;
    u.x = cvtpk(f0.x, f0.y); u.y = cvtpk(f0.z, f0.w);
    u.z = cvtpk(f1.x, f1.y); u.w = cvtpk(f1.z, f1.w);
    a[ks] = __builtin_bit_cast(bf16x8, u);
  }

  f32x4 acc[4] = {};
  #pragma unroll
  for (int cb = 0; cb < 4; ++cb) {
    #pragma unroll
    for (int ks = 0; ks < 2; ++ks) {
      // B[k=d][col=e]: lane(c,g) reads Wb[e=cb*16+c][d=ks*32+g*8 ..+7]
      const bf16x8 b = *(const bf16x8*)(W + (cb * 16 + c) * HD + ks * 32 + g * 8);
      acc[cb] = __builtin_amdgcn_mfma_f32_16x16x32_bf16(a[ks], b, acc[cb], 0, 0, 0);
    }
  }

  // acc[cb][r] = out[row = lb*16+4g+r][e = cb*16+c]
  if (t == 0) {
    // V^T[e][key]: keys 4g+r are consecutive -> 8B store per cb
    unsigned short* vt = out + (size_t)(n * HEADS + h) * (HD * SEQ);
    const int key0 = lb * 16 + 4 * g;
    #pragma unroll
    for (int cb = 0; cb < 4; ++cb) {
      const unsigned w0 = cvtpk(acc[cb][0], acc[cb][1]);
      const unsigned w1 = cvtpk(acc[cb][2], acc[cb][3]);
      *(uint2*)(vt + (size_t)(cb * 16 + c) * SEQ + key0) = make_uint2(w0, w1);
    }
  } else {
    unsigned short* op = out + ((size_t)(n * HEADS + h) * SEQ + lb * 16) * HD;
    #pragma unroll
    for (int r = 0; r < 4; ++r) {
      const unsigned w0 = cvtpk(acc[0][r], acc[1][r]);
      const unsigned w1 = cvtpk(acc[2][r], acc[3][r]);
      *(uint2*)(op + (4 * g + r) * HD + 4 * c) = make_uint2(w0, w1);
    }
  }
}

// ---------------- flash attention, swapped QK^T, fully in-register P ----------------
// block = (n, h, 64 q-rows); 4 waves x 16 q-rows. Grid 1024 (4/CU), bid%8 = nh%8 (XCD).
// S^T = mfma(A=K, B=Q): lane(c,g) holds S[key=kappa(sub,4g+r)][qrow=c] where
//   kappa(sub,i) = (sub&1)*32 + (sub>>1)*4 + 8*(i>>2) + (i&3)
// chosen so {kappa(sub,4g+r)} = PV A-frag keys {32ks+8g+j} exactly (no cross-lane).
// Key permutation applied in the K staging SOURCE address (LDS stays linear).
__global__ __launch_bounds__(256, 4) void k_attn(const unsigned short* __restrict__ qb,
                                                 const unsigned short* __restrict__ kb,
                                                 const unsigned short* __restrict__ vb,
                                                 const unsigned long long* __restrict__ mb,
                                                 unsigned short* __restrict__ ob) {
  const int tid = threadIdx.x;
  const int w = tid >> 6, lane = tid & 63;
  const int c = lane & 15, g = lane >> 4;
  const int bid = blockIdx.x;
  const int nh = bid & 63, q64 = bid >> 6;
  const int n = nh >> 4, h = nh & 15;
  const int qlo = q64 * 64 + w * 16;

  __shared__ unsigned short Ks[2][64][64];   // A-row rho holds key kappa(rho); col-swz ^(rho&7)
  __shared__ unsigned short Vs[2][64][64];   // V^T[d][keypos], col-swz ^(row&7)

  char* const Kb0 = (char*)&Ks[0][0][0];
  char* const Vb0 = (char*)&Vs[0][0][0];

  const size_t nhb = (size_t)(n * HEADS + h) * (SEQ * HD);
  const unsigned short* qp = qb + nhb;
  const char* kpB = (const char*)(kb + nhb);
  const char* vpB = (const char*)(vb + nhb);   // V^T [64][1024], row pitch 2048B

  // Q B-frags: lane(c,g) = Q[qrow=qlo+c][dpos=ks*32+8g+j]
  bf16x8 qa[2];
  #pragma unroll
  for (int ks = 0; ks < 2; ++ks)
    qa[ks] = *(const bf16x8*)(qp + (size_t)(qlo + c) * HD + ks * 32 + g * 8);

  bf16x8 ones;
  #pragma unroll
  for (int j = 0; j < 8; ++j) ones[j] = (short)0x3F80;

  f32x4 o[4] = {};
  f32x4 lacc = {};

#define STAGEKV(dstK, dstV, kt_) do {                                                   \
    _Pragma("unroll")                                                                   \
    for (int i = 0; i < 2; ++i) {                                                       \
      const int off = i * 4096 + tid * 16;                                              \
      const int row = off >> 7, slot = (off >> 4) & 7;                                  \
      const int krow = ((row >> 4) & 1) * 32 + ((row >> 5) & 1) * 4 +                   \
                       ((row >> 2) & 3) * 8 + (row & 3);                                \
      const int sw = (slot ^ (row & 7)) << 4;                                           \
      gload_lds16(kpB + (size_t)(kt_) * 8192 + krow * 128 + sw, (dstK) + off);          \
      gload_lds16(vpB + (size_t)row * 2048 + (kt_) * 128 + sw, (dstV) + off);           \
    }                                                                                   \
  } while (0)

  STAGEKV(Kb0, Vb0, 0);
  __syncthreads();

  for (int kt = 0; kt < 16; ++kt) {
    const int cur = kt & 1;
    char* const Kc = Kb0 + cur * 8192;
    char* const Vc = Vb0 + cur * 8192;
    if (kt < 15) STAGEKV(Kb0 + (cur ^ 1) * 8192, Vb0 + (cur ^ 1) * 8192, kt + 1);

    // mask row for this lane's qrow (=qlo+c)
    const unsigned long long bits = mb[((size_t)(n * 16 + kt)) * 1024 + qlo + c];
    const unsigned blo = (unsigned)bits, bhi = (unsigned)(bits >> 32);

    // K A-frags: kf[sub][ks] lane(c,g) = A[row=c] of subtile sub = K[kappa(sub,c)]
    bf16x8 kf[4][2];
    #pragma unroll
    for (int sub = 0; sub < 4; ++sub) {
      const int rho = sub * 16 + c;     // rho&7 == c&7
      #pragma unroll
      for (int ks = 0; ks < 2; ++ks)
        kf[sub][ks] = *(const bf16x8*)(Kc + rho * 128 + (((ks * 4 + g) ^ (c & 7)) << 4));
    }

    // V^T B-frags: vf[db][ks] lane(c,g) = V^T[d=db*16+c][key=ks*32+8g+j]
    bf16x8 vf[4][2];
    #pragma unroll
    for (int db = 0; db < 4; ++db) {
      const int row = db * 16 + c;
      #pragma unroll
      for (int ks = 0; ks < 2; ++ks)
        vf[db][ks] = *(const bf16x8*)(Vc + row * 128 + (((ks * 4 + g) ^ (c & 7)) << 4));
    }

    // S^T = K * Q^T : s[sub] lane(c,g) = S[key=kappa(sub,4g+r)][qrow=c]
    f32x4 s[4];
    __builtin_amdgcn_s_setprio(1);
    #pragma unroll
    for (int sub = 0; sub < 4; ++sub) {
      f32x4 acc = {};
      acc = __builtin_amdgcn_mfma_f32_16x16x32_bf16(kf[sub][0], qa[0], acc, 0, 0, 0);
      acc = __builtin_amdgcn_mfma_f32_16x16x32_bf16(kf[sub][1], qa[1], acc, 0, 0, 0);
      s[sub] = acc;
    }
    __builtin_amdgcn_s_setprio(0);

    // softmax numerators, in-register, directly into PV A-frag word order
    unsigned pw[2][4];
    #pragma unroll
    for (int sub = 0; sub < 4; ++sub) {
      const unsigned x = ((sub & 1) ? bhi : blo) >> (8 * g + ((sub >> 1) << 2));
      const float p0 = (x & 1u) ? __builtin_exp2f(s[sub][0]) : 0.f;
      const float p1 = (x & 2u) ? __builtin_exp2f(s[sub][1]) : 0.f;
      const float p2 = (x & 4u) ? __builtin_exp2f(s[sub][2]) : 0.f;
      const float p3 = (x & 8u) ? __builtin_exp2f(s[sub][3]) : 0.f;
      pw[sub & 1][(sub >> 1) * 2 + 0] = cvtpk(p0, p1);
      pw[sub & 1][(sub >> 1) * 2 + 1] = cvtpk(p2, p3);
    }
    bf16x8 pa[2];
    pa[0] = __builtin_bit_cast(bf16x8, *(uint4*)&pw[0][0]);
    pa[1] = __builtin_bit_cast(bf16x8, *(uint4*)&pw[1][0]);

    // O += P V ; l += P * ones
    __builtin_amdgcn_s_setprio(1);
    #pragma unroll
    for (int ks = 0; ks < 2; ++ks) {
      #pragma unroll
      for (int db = 0; db < 4; ++db)
        o[db] = __builtin_amdgcn_mfma_f32_16x16x32_bf16(pa[ks], vf[db][ks], o[db], 0, 0, 0);
      lacc = __builtin_amdgcn_mfma_f32_16x16x32_bf16(pa[ks], ones, lacc, 0, 0, 0);
    }
    __builtin_amdgcn_s_setprio(0);

    __syncthreads();
  }
#undef STAGEKV

  // epilogue: lane(c,g) holds O[qrow=4g+r][e=db*16+c], l[qrow=4g+r]
  #pragma unroll
  for (int r = 0; r < 4; ++r) {
    const float inv = 1.0f / lacc[r];
    const unsigned w0 = cvtpk(o[0][r] * inv, o[1][r] * inv);
    const unsigned w1 = cvtpk(o[2][r] * inv, o[3][r] * inv);
    *(uint2*)(ob + ((size_t)n * SEQ + qlo + 4 * g + r) * EMB + h * 64 + 4 * c) =
        make_uint2(w0, w1);
  }
}

// ---------------- out-proj GEMM: C[4096,1024] = A[4096,1024pi] * B[1024,1024pi]^T + bo ----------------
// 64x64 tile, BK=64, grid 1024 (4/CU), swizzled dbuf LDS, bid%8 = bm%8 (XCD: A-band locality).
__global__ __launch_bounds__(256, 4) void k_gemm(const unsigned short* __restrict__ A,
                                                 const unsigned short* __restrict__ B,
                                                 const float* __restrict__ bo,
                                                 float* __restrict__ C) {
  const int tid = threadIdx.x;
  const int w = tid >> 6, lane = tid & 63;
  const int c = lane & 15, g = lane >> 4;
  const int bm = blockIdx.x & 63, bn = blockIdx.x >> 6;
  const int m0 = bm * 64, n0 = bn * 64;
  const int wr = w >> 1, wc = w & 1;

  __shared__ unsigned short As[2][64][64];
  __shared__ unsigned short Bs[2][64][64];

  f32x4 acc[2][2] = {};

#define STAGE(buf, kt_) do {                                                             \
    _Pragma("unroll")                                                                    \
    for (int i = 0; i < 2; ++i) {                                                        \
      const int off = i * 4096 + tid * 16;                                               \
      const int row = off >> 7, slot = (off >> 4) & 7;                                   \
      const int sw = (slot ^ (row & 7)) << 4;                                            \
      gload_lds16((const char*)A + ((size_t)(m0 + row) * 1024 + (kt_) * 64) * 2 + sw,    \
                  (char*)&As[buf][0][0] + off);                                          \
      gload_lds16((const char*)B + ((size_t)(n0 + row) * 1024 + (kt_) * 64) * 2 + sw,    \
                  (char*)&Bs[buf][0][0] + off);                                          \
    }                                                                                    \
  } while (0)

  STAGE(0, 0);
  __syncthreads();

  for (int kt = 0; kt < 16; ++kt) {
    const int cur = kt & 1;
    if (kt < 15) STAGE(cur ^ 1, kt + 1);
    #pragma unroll
    for (int ks = 0; ks < 2; ++ks) {
      bf16x8 af[2], bf_[2];
      #pragma unroll
      for (int i = 0; i < 2; ++i) {
        const int row = wr * 32 + i * 16 + c;   // row&7 == c&7
        af[i] = *(const bf16x8*)((char*)&As[cur][0][0] + row * 128 +
                                 (((ks * 4 + g) ^ (c & 7)) << 4));
      }
      #pragma unroll
      for (int j = 0; j < 2; ++j) {
        const int row = wc * 32 + j * 16 + c;
        bf_[j] = *(const bf16x8*)((char*)&Bs[cur][0][0] + row * 128 +
                                  (((ks * 4 + g) ^ (c & 7)) << 4));
      }
      __builtin_amdgcn_s_setprio(1);
      #pragma unroll
      for (int i = 0; i < 2; ++i)
        #pragma unroll
        for (int j = 0; j < 2; ++j)
          acc[i][j] = __builtin_amdgcn_mfma_f32_16x16x32_bf16(af[i], bf_[j], acc[i][j], 0, 0, 0);
      __builtin_amdgcn_s_setprio(0);
    }
    __syncthreads();
  }
#undef STAGE

  #pragma unroll
  for (int j = 0; j < 2; ++j) {
    const int col = n0 + wc * 32 + j * 16 + c;
    const float bv = bo[col];
    #pragma unroll
    for (int i = 0; i < 2; ++i) {
      const int rowb = m0 + wr * 32 + i * 16 + 4 * g;
      #pragma unroll
      for (int r = 0; r < 4; ++r)
        C[(size_t)(rowb + r) * 1024 + col] = acc[i][j][r] + bv;
    }
  }
}

extern "C" void kernel_launch(void* const* d_in, const int* in_sizes, int n_in,
                              void* d_out, int out_size, void* d_ws, size_t ws_size,
                              hipStream_t stream) {
  const float* values = (const float*)d_in[0];
  const float* query  = (const float*)d_in[1];
  const float* key    = (const float*)d_in[2];
  const int*   mask   = (const int*)d_in[3];
  const float* Wv     = (const float*)d_in[4];
  const float* Wk     = (const float*)d_in[5];
  const float* Wq     = (const float*)d_in[6];
  const float* Wo     = (const float*)d_in[7];
  const float* bo     = (const float*)d_in[8];
  float* out = (float*)d_out;

  char* ws = (char*)d_ws;
  unsigned short* qb = (unsigned short*)(ws);                            // 8MB  [N][H][S][Dpi]
  unsigned short* kb = (unsigned short*)(ws + (size_t)8 * 1024 * 1024);  // 8MB  [N][H][S][Dpi]
  unsigned short* vb = (unsigned short*)(ws + (size_t)16 * 1024 * 1024); // 8MB  V^T [N][H][D][S]
  unsigned short* ob = (unsigned short*)(ws + (size_t)24 * 1024 * 1024); // 8MB  [N][S][Epi]
  unsigned long long* mb = (unsigned long long*)(ws + (size_t)32 * 1024 * 1024);   // 512KB
  unsigned short* wb  = (unsigned short*)(ws + (size_t)32 * 1024 * 1024 + 512 * 1024); // 24KB
  unsigned short* wob = (unsigned short*)(ws + (size_t)33 * 1024 * 1024);          // 2MB

  k_maskpack<<<16384, 256, 0, stream>>>(mask, mb);
  k_cvtwo<<<1025, 256, 0, stream>>>(Wo, Wv, Wq, Wk, wob, wb);
  k_proj<<<3072, 256, 0, stream>>>(values, query, key, wb, vb, qb, kb);
  k_attn<<<1024, 256, 0, stream>>>(qb, kb, vb, mb, ob);
  k_gemm<<<1024, 256, 0, stream>>>(ob, wob, bo, out);
}